// Round 12
// baseline (246.800 us; speedup 1.0000x reference)
//
#include <hip/hip_runtime.h>
#include <math.h>

#define BATCH 64
#define NOBJ  64
#define DDIM  128
#define HDIM  256
#define ROWS  (BATCH*NOBJ)    // 4096
#define PAIRS (ROWS*NOBJ)     // 262144

// ---- workspace layout (bytes) ----
#define OFF_A_REL    (0ull)
#define OFF_B_REL    (4ull<<20)
#define OFF_A_WGT    (8ull<<20)      // f32
#define OFF_B_WGT    (12ull<<20)     // f32 (row-major, for bn_stats)
#define OFF_BWT      (16ull<<20)     // f32 transposed [b][k][j] (for k_main)
#define OFF_H_SELF   (20ull<<20)
#define OFF_ENC_SELF (24ull<<20)
#define OFF_ENC_REL  (26ull<<20)
#define OFF_H_PRED   (28ull<<20)
#define OFF_WIHT     (30ull<<20)           // 384x256 f32 transposed gru_wih
#define OFF_WHHT     (OFF_WIHT + 400*1024) // 384x128 f32 transposed gru_whh
#define OFF_STATS    (32ull<<20)     // 8 x 256 doubles
#define OFF_KLP      (OFF_STATS + 16384)   // 1024 f32 partials
#define OFF_W2P      (OFF_STATS + 65536)   // rel folded w2: 256x128 f32
#define OFF_C2       (OFF_W2P + 128*1024)  // 128 f32
#define OFF_W2PD     (OFF_C2 + 512)        // wgt folded w2: 512 f64
#define OFF_C2W      (OFF_W2PD + 4096)     // 2 f64
#define OFF_SW2P     (OFF_C2W + 256)       // self folded w2
#define OFF_SC2      (OFF_SW2P + 128*1024)

// ---- output layout (floats) ----
#define OUT_UPD 0
#define OUT_ZWN (ROWS*DDIM)          // 524288
#define OUT_WGT (OUT_ZWN + ROWS*2)   // 532480
#define OUT_KL  (OUT_WGT + PAIRS)    // 794624

// zero the stats accumulators
__global__ __launch_bounds__(256) void k_zero(double* __restrict__ p)
{
    p[blockIdx.x*256 + threadIdx.x] = 0.0;
}

// transpose GRU weights: wihT[c][k] = wih[k][c], whhT[c][k] = whh[k][c]
__global__ __launch_bounds__(256) void k_wtrans(
    const float* __restrict__ wih, const float* __restrict__ whh,
    float* __restrict__ wihT, float* __restrict__ whhT)
{
    const int c = blockIdx.x;        // 0..383
    const int k = threadIdx.x;       // 0..255
    wihT[c*256 + k] = wih[k*384 + c];
    if (k < 128) whhT[c*128 + k] = whh[k*384 + c];
}

// GEMM-tiled pre-activations, pair-merged, 8 rows/block (R10 version).
__global__ __launch_bounds__(256) void k_pre(
    const float* __restrict__ states,
    const float* __restrict__ rel_w1, const float* __restrict__ rel_b1,
    const float* __restrict__ wgt_w1, const float* __restrict__ wgt_b1,
    const float* __restrict__ z_where, const float* __restrict__ actions,
    const float* __restrict__ self_w1, const float* __restrict__ self_b1,
    float* __restrict__ A_rel, float* __restrict__ B_rel,
    float* __restrict__ A_wgt, float* __restrict__ B_wgt,
    float* __restrict__ B_wgtT, float* __restrict__ h_self,
    double* __restrict__ stats)
{
    const int t = threadIdx.x;
    const int view = blockIdx.y;

    if (view == 2) {
        if (blockIdx.x >= 256) return;
        const int row0 = blockIdx.x * 16;
        const float w_zw0 = self_w1[0*256+t], w_zw1 = self_w1[1*256+t];
        const float w_a0  = self_w1[66*256+t], w_a1 = self_w1[67*256+t];
        const float bb1 = self_b1[t];
        double sum = 0.0, ssq = 0.0;
        for (int r = 0; r < 16; ++r) {
            const int row = row0 + r;
            const int b = row >> 6, i = row & 63;
            const float zw0 = z_where[row*2], zw1 = z_where[row*2+1];
            const float a0 = actions[b*2], a1 = actions[b*2+1];
            float v = self_w1[(2+i)*256+t] + bb1;
            v = fmaf(zw0, w_zw0, v); v = fmaf(zw1, w_zw1, v);
            v = fmaf(a0, w_a0, v);   v = fmaf(a1, w_a1, v);
            v = fmaxf(v, 0.f);
            h_self[row*256+t] = v;
            sum += (double)v; ssq = fma((double)v, (double)v, ssq);
        }
        atomicAdd(&stats[4*256+t], sum);
        atomicAdd(&stats[5*256+t], ssq);
        return;
    }

    const int row0 = blockIdx.x * 8;
    __shared__ float s_tile[8][128];
    for (int f4 = t; f4 < 256; f4 += 256)
        *(float4*)&s_tile[0][f4*4] = *(const float4*)&states[row0*128 + f4*4];
    __syncthreads();

    const float* wbase = (view == 0) ? rel_w1 : wgt_w1;
    const float* wpA = wbase + t;
    const float* wpB = wbase + 128*256 + t;
    float accA[8], accB[8];
#pragma unroll
    for (int r = 0; r < 8; ++r) { accA[r] = 0.f; accB[r] = 0.f; }
#pragma unroll 4
    for (int k = 0; k < 128; ++k) {
        const float wvA = wpA[k*256];
        const float wvB = wpB[k*256];
#pragma unroll
        for (int r = 0; r < 8; ++r) {
            const float s = s_tile[r][k];
            accA[r] = fmaf(s, wvA, accA[r]);
            accB[r] = fmaf(s, wvB, accB[r]);
        }
    }

    if (view == 0) {
        const float bias = rel_b1[t];
#pragma unroll
        for (int r = 0; r < 8; ++r) {
            A_rel[(row0+r)*256 + t] = accA[r] + bias;
            B_rel[(row0+r)*256 + t] = accB[r];
        }
    } else {
        const float bias = wgt_b1[t];
#pragma unroll
        for (int r = 0; r < 8; ++r) {
            A_wgt[(row0+r)*256 + t] = accA[r] + bias;
            B_wgt[(row0+r)*256 + t] = accB[r];
        }
        const int b = row0 >> 6, j0 = row0 & 63;
        float* bt = &B_wgtT[((size_t)b*256 + t)*64 + j0];
        *(float4*)(bt+0) = make_float4(accB[0], accB[1], accB[2], accB[3]);
        *(float4*)(bt+4) = make_float4(accB[4], accB[5], accB[6], accB[7]);
    }
}

// BN stats over all 262144 pairs. rel: f32; wgt: f64 (argmax-critical). R4 config.
__global__ __launch_bounds__(256) void k_bn_stats(
    const float* __restrict__ A_rel, const float* __restrict__ B_rel,
    const float* __restrict__ A_wgt, const float* __restrict__ B_wgt,
    double* __restrict__ stats)
{
    const int h = threadIdx.x;
    const int b = blockIdx.y, i0 = blockIdx.x * 8;
    float ar[8], aw[8];
#pragma unroll
    for (int r = 0; r < 8; ++r) {
        ar[r] = A_rel[(b*64 + i0 + r)*256 + h];
        aw[r] = A_wgt[(b*64 + i0 + r)*256 + h];
    }
    float  srel0 = 0.f, ssrel0 = 0.f, srel1 = 0.f, ssrel1 = 0.f;
    double swgt = 0.0, sswgt = 0.0;
    for (int j = 0; j < 64; j += 2) {
        const float br0 = B_rel[(b*64+j)*256 + h];
        const float bw0 = B_wgt[(b*64+j)*256 + h];
        const float br1 = B_rel[(b*64+j+1)*256 + h];
        const float bw1 = B_wgt[(b*64+j+1)*256 + h];
#pragma unroll
        for (int r = 0; r < 8; ++r) {
            const float v0 = fmaxf(ar[r] + br0, 0.f);
            srel0 += v0; ssrel0 = fmaf(v0, v0, ssrel0);
            const float vw0 = fmaxf(aw[r] + bw0, 0.f);
            swgt += (double)vw0; sswgt = fma((double)vw0, (double)vw0, sswgt);
        }
#pragma unroll
        for (int r = 0; r < 8; ++r) {
            const float v1 = fmaxf(ar[r] + br1, 0.f);
            srel1 += v1; ssrel1 = fmaf(v1, v1, ssrel1);
            const float vw1 = fmaxf(aw[r] + bw1, 0.f);
            swgt += (double)vw1; sswgt = fma((double)vw1, (double)vw1, sswgt);
        }
    }
    atomicAdd(&stats[0*256+h], (double)(srel0 + srel1));
    atomicAdd(&stats[1*256+h], (double)(ssrel0 + ssrel1));
    atomicAdd(&stats[2*256+h], swgt);
    atomicAdd(&stats[3*256+h], sswgt);
}

// fold BN scale/shift into layer-2 weights; grid = 4 blocks
__global__ __launch_bounds__(256) void k_finalize(
    const double* __restrict__ stats,
    const float* __restrict__ rel_g, const float* __restrict__ rel_bb,
    const float* __restrict__ rel_w2, const float* __restrict__ rel_b2,
    const float* __restrict__ wgt_g, const float* __restrict__ wgt_bb,
    const float* __restrict__ wgt_w2, const float* __restrict__ wgt_b2,
    const float* __restrict__ self_g, const float* __restrict__ self_bb,
    const float* __restrict__ self_w2, const float* __restrict__ self_b2,
    float* __restrict__ W2p, float* __restrict__ c2,
    double* __restrict__ W2pd, double* __restrict__ c2w,
    float* __restrict__ sW2p, float* __restrict__ sc2)
{
    __shared__ float  rscale[256], rshift[256], sscale[256], sshift[256];
    __shared__ double wshift[256];
    const int k = threadIdx.x;
    {
        const double cnt = 262144.0;
        double mu  = stats[0*256+k]/cnt;
        double var = stats[1*256+k]/cnt - mu*mu;
        float  sc  = (float)((double)rel_g[k] / sqrt(var + 1e-5));
        rscale[k] = sc;
        rshift[k] = rel_bb[k] - (float)mu * sc;
        double muw  = stats[2*256+k]/cnt;
        double varw = stats[3*256+k]/cnt - muw*muw;
        double scw  = (double)wgt_g[k] / sqrt(varw + 1e-5);
        wshift[k]   = (double)wgt_bb[k] - muw*scw;
        if (blockIdx.x == 0) {
            W2pd[2*k]   = scw * (double)wgt_w2[2*k];
            W2pd[2*k+1] = scw * (double)wgt_w2[2*k+1];
        }
        const double cnts = 4096.0;
        double mus  = stats[4*256+k]/cnts;
        double vars = stats[5*256+k]/cnts - mus*mus;
        float  scs  = (float)((double)self_g[k] / sqrt(vars + 1e-5));
        sscale[k] = scs;
        sshift[k] = self_bb[k] - (float)mus*scs;
    }
    __syncthreads();
    const int base = blockIdx.x * 8192;
    for (int idx = base + k; idx < base + 8192; idx += 256) {
        const int kk = idx >> 7;
        W2p[idx]  = rscale[kk]*rel_w2[idx];
        sW2p[idx] = sscale[kk]*self_w2[idx];
    }
    if (blockIdx.x == 0) {
        if (k < 128) {
            float acc = rel_b2[k], accs = self_b2[k];
            for (int kk = 0; kk < 256; ++kk) {
                acc  = fmaf(rshift[kk], rel_w2[kk*128+k], acc);
                accs = fmaf(sshift[kk], self_w2[kk*128+k], accs);
            }
            c2[k] = acc; sc2[k] = accs;
        }
        if (k < 2) {
            double acc = (double)wgt_b2[k];
            for (int kk = 0; kk < 256; ++kk) acc += wshift[kk]*(double)wgt_w2[kk*2+k];
            c2w[k] = acc;
        }
    }
}

// 4 rows per block; 1024 blocks, 256 threads.
__global__ __launch_bounds__(256) void k_main(
    const float* __restrict__ A_rel, const float* __restrict__ B_rel,
    const float* __restrict__ A_wgt, const float* __restrict__ B_wgtT,
    const double* __restrict__ W2pd, const double* __restrict__ c2w,
    const float* __restrict__ gumbel,
    const float* __restrict__ W2p, const float* __restrict__ c2,
    float* __restrict__ enc_rel, float* __restrict__ weight_out,
    float* __restrict__ klp)
{
    __shared__ float  a_lds[4][256];
    __shared__ double w2_lds[512];
    __shared__ double red0[4][4][64], red1[4][4][64];
    __shared__ float  w_lds[4][64];
    __shared__ float  klred[256];
    __shared__ float  h_lds[4][256];
    __shared__ float  redf[4][256];
    const int t = threadIdx.x;
    const int blk = blockIdx.x;          // 0..1023
    const int row0 = blk * 4;
    const int b = row0 >> 6;

    w2_lds[t]     = W2pd[t];
    w2_lds[256+t] = W2pd[256+t];
    float a_rel[4];
#pragma unroll
    for (int r = 0; r < 4; ++r) {
        a_lds[r][t] = A_wgt[(row0+r)*256 + t];
        a_rel[r]    = A_rel[(row0+r)*256 + t];
    }
    __syncthreads();

    // ---- phase A: logits, k wave-uniform (f64 accumulation) ----
    {
        const int j = t & 63, q = t >> 6;
        double acc0[4] = {0,0,0,0}, acc1[4] = {0,0,0,0};
        const float* btp = &B_wgtT[((size_t)b*256 + q*64)*64 + j];
#pragma unroll 4
        for (int kk = 0; kk < 64; ++kk) {
            const int k = q*64 + kk;
            const float  bw = btp[kk*64];
            const double w0 = w2_lds[2*k], w1 = w2_lds[2*k+1];
#pragma unroll
            for (int r = 0; r < 4; ++r) {
                const double hw = (double)fmaxf(a_lds[r][k] + bw, 0.f);
                acc0[r] = fma(hw, w0, acc0[r]);
                acc1[r] = fma(hw, w1, acc1[r]);
            }
        }
#pragma unroll
        for (int r = 0; r < 4; ++r) { red0[r][q][j] = acc0[r]; red1[r][q][j] = acc1[r]; }
    }
    __syncthreads();

    // ---- finalize logits: t -> (r, j); weight + KL ----
    {
        const int r = t >> 6, j = t & 63;
        const double l0 = red0[r][0][j]+red0[r][1][j]+red0[r][2][j]+red0[r][3][j] + c2w[0];
        const double l1 = red1[r][0][j]+red1[r][1][j]+red1[r][2][j]+red1[r][3][j] + c2w[1];
        const int row = row0 + r;
        const float g0 = gumbel[(row*64+j)*2], g1 = gumbel[(row*64+j)*2+1];
        float w = (l0 + (double)g0 >= l1 + (double)g1) ? 1.f : 0.f;
        if (j == (row & 63)) w = 0.f;      // (1-eye) mask
        w_lds[r][j] = w;
        weight_out[row*64 + j] = w;
        const float lf0 = (float)l0, lf1 = (float)l1;
        const float m = fmaxf(lf0, lf1);
        const float e0 = expf(lf0 - m), e1 = expf(lf1 - m);
        const float s = e0 + e1;
        const float p0 = e0/s, p1 = e1/s;
        const float lp0 = -2.9957323f;   // log(0.05)
        const float lp1 = -0.05129329f;  // log(0.95)
        klred[t] = p0*(logf(p0+1e-16f) - lp0) + p1*(logf(p1+1e-16f) - lp1);
    }
    __syncthreads();
    if (t < 64) {
        float s = klred[t] + klred[t+64] + klred[t+128] + klred[t+192];
        for (int off = 32; off; off >>= 1) s += __shfl_down(s, off);
        if (t == 0) klp[blk] = s;
    }

    // ---- phase B: weighted relu accumulation (t = k), branch-free ----
    float sumw[4] = {0,0,0,0};
    {
        float g[4] = {0,0,0,0};
#pragma unroll 4
        for (int j = 0; j < 64; ++j) {
            const float br = B_rel[(b*64+j)*256 + t];
#pragma unroll
            for (int r = 0; r < 4; ++r) {
                const float w = w_lds[r][j];
                sumw[r] += w;
                g[r] = fmaf(w, fmaxf(a_rel[r] + br, 0.f), g[r]);
            }
        }
#pragma unroll
        for (int r = 0; r < 4; ++r) h_lds[r][t] = g[r];
    }
    __syncthreads();
    // ---- folded matvec 256->128, amortized over 4 rows ----
    {
        const int d = t & 127, half = t >> 7;
        float acc[4] = {0,0,0,0};
        const float* wp = &W2p[half*128*128 + d];
#pragma unroll 2
        for (int kk = 0; kk < 128; ++kk) {
            const float wv = wp[kk*128];
#pragma unroll
            for (int r = 0; r < 4; ++r)
                acc[r] = fmaf(h_lds[r][half*128 + kk], wv, acc[r]);
        }
#pragma unroll
        for (int r = 0; r < 4; ++r) redf[r][t] = acc[r];
    }
    __syncthreads();
    if (t < 128) {
#pragma unroll
        for (int r = 0; r < 4; ++r)
            enc_rel[(row0+r)*128 + t] = redf[r][t] + redf[r][t+128] + sumw[r]*c2[t];
    }
}

// enc_self = BN(h_self) @ self_w2 + b2 via folded weights; 16 rows/block (R10)
__global__ __launch_bounds__(256) void k_enc_self(
    const float* __restrict__ h_self, const float* __restrict__ sW2p,
    const float* __restrict__ sc2, float* __restrict__ enc_self)
{
    __shared__ float h_lds[16*256];
    const int t = threadIdx.x;
    const int row0 = blockIdx.x * 16;
    for (int f4 = t; f4 < 1024; f4 += 256)
        *(float4*)&h_lds[f4*4] = *(const float4*)&h_self[row0*256 + f4*4];
    __syncthreads();
    const int d = t & 127, half = t >> 7;
    float acc[16];
#pragma unroll
    for (int r = 0; r < 16; ++r) acc[r] = 0.f;
    for (int kk = 0; kk < 128; ++kk) {
        const int k = half*128 + kk;
        const float wv = sW2p[k*128 + d];
#pragma unroll
        for (int r = 0; r < 16; ++r) acc[r] = fmaf(h_lds[r*256 + k], wv, acc[r]);
    }
    __syncthreads();
#pragma unroll
    for (int r = 0; r < 16; ++r) h_lds[r*256 + t] = acc[r];
    __syncthreads();
    for (int idx = t; idx < 16*128; idx += 256) {
        const int r = idx >> 7, dd = idx & 127;
        enc_self[(row0+r)*128 + dd] = h_lds[r*256 + dd] + h_lds[r*256 + 128 + dd] + sc2[dd];
    }
}

// GRU cell v7: v6 geometry (192 threads, 2 cols/thread, 4 rows, 1024 blocks)
// with float4 weight loads from pre-transposed wihT/whhT (768 -> 192 VMEM
// instrs/thread). Per-column k-ascending FMA chains identical to v6 -> bit-exact.
__global__ __launch_bounds__(192) void k_gru(
    const float* __restrict__ enc_self, const float* __restrict__ enc_rel,
    const float* __restrict__ states,
    const float* __restrict__ wihT, const float* __restrict__ whhT,
    const float* __restrict__ bih, const float* __restrict__ bhh,
    float* __restrict__ updated)
{
    __shared__ float x_lds[4][256];
    __shared__ float s_lds[4][128];
    __shared__ float gi_lds[4][384];
    __shared__ float gh_lds[4][384];
    const int t = threadIdx.x;
    const int row0 = blockIdx.x * 4;
    for (int idx = t; idx < 4*256; idx += 192) {
        const int r = idx >> 8, k = idx & 255;
        x_lds[r][k] = (k < 128) ? enc_self[(row0+r)*128 + k]
                                : enc_rel[(row0+r)*128 + (k-128)];
    }
    for (int idx = t; idx < 4*128; idx += 192) {
        const int r = idx >> 7, k = idx & 127;
        s_lds[r][k] = states[(row0+r)*128 + k];
    }
    __syncthreads();
    const int c0 = t, c1 = t + 192;
    float gi0[4], gh0[4], gi1[4], gh1[4];
    const float bi0 = bih[c0], bh0 = bhh[c0];
    const float bi1 = bih[c1], bh1 = bhh[c1];
#pragma unroll
    for (int r = 0; r < 4; ++r) { gi0[r] = bi0; gh0[r] = bh0; gi1[r] = bi1; gh1[r] = bh1; }

    const float* wiT0 = &wihT[(size_t)c0*256];
    const float* wiT1 = &wihT[(size_t)c1*256];
    const float* whT0 = &whhT[(size_t)c0*128];
    const float* whT1 = &whhT[(size_t)c1*128];

    // ---- phase 1: k = 0..127, both streams ----
    for (int k0 = 0; k0 < 128; k0 += 4) {
        float4 xv[4], sv[4];
#pragma unroll
        for (int r = 0; r < 4; ++r) {
            xv[r] = *(const float4*)&x_lds[r][k0];
            sv[r] = *(const float4*)&s_lds[r][k0];
        }
        const float4 wi0 = *(const float4*)&wiT0[k0];
        const float4 wi1 = *(const float4*)&wiT1[k0];
        const float4 wh0 = *(const float4*)&whT0[k0];
        const float4 wh1 = *(const float4*)&whT1[k0];
        const float wi0a[4] = {wi0.x, wi0.y, wi0.z, wi0.w};
        const float wi1a[4] = {wi1.x, wi1.y, wi1.z, wi1.w};
        const float wh0a[4] = {wh0.x, wh0.y, wh0.z, wh0.w};
        const float wh1a[4] = {wh1.x, wh1.y, wh1.z, wh1.w};
#pragma unroll
        for (int kk = 0; kk < 4; ++kk) {
#pragma unroll
            for (int r = 0; r < 4; ++r) {
                const float x = ((const float*)&xv[r])[kk];
                const float s = ((const float*)&sv[r])[kk];
                gi0[r] = fmaf(x, wi0a[kk], gi0[r]);
                gi1[r] = fmaf(x, wi1a[kk], gi1[r]);
                gh0[r] = fmaf(s, wh0a[kk], gh0[r]);
                gh1[r] = fmaf(s, wh1a[kk], gh1[r]);
            }
        }
    }
    // ---- phase 2: k = 128..255, gi only ----
    for (int k0 = 128; k0 < 256; k0 += 4) {
        float4 xv[4];
#pragma unroll
        for (int r = 0; r < 4; ++r)
            xv[r] = *(const float4*)&x_lds[r][k0];
        const float4 wi0 = *(const float4*)&wiT0[k0];
        const float4 wi1 = *(const float4*)&wiT1[k0];
        const float wi0a[4] = {wi0.x, wi0.y, wi0.z, wi0.w};
        const float wi1a[4] = {wi1.x, wi1.y, wi1.z, wi1.w};
#pragma unroll
        for (int kk = 0; kk < 4; ++kk) {
#pragma unroll
            for (int r = 0; r < 4; ++r) {
                const float x = ((const float*)&xv[r])[kk];
                gi0[r] = fmaf(x, wi0a[kk], gi0[r]);
                gi1[r] = fmaf(x, wi1a[kk], gi1[r]);
            }
        }
    }
#pragma unroll
    for (int r = 0; r < 4; ++r) {
        gi_lds[r][c0] = gi0[r]; gi_lds[r][c1] = gi1[r];
        gh_lds[r][c0] = gh0[r]; gh_lds[r][c1] = gh1[r];
    }
    __syncthreads();
    for (int idx = t; idx < 4*128; idx += 192) {
        const int r = idx >> 7, d = idx & 127;
        const float gr = gi_lds[r][d]       + gh_lds[r][d];
        const float gz = gi_lds[r][128+d]   + gh_lds[r][128+d];
        const float rr = 1.f/(1.f + expf(-gr));
        const float zz = 1.f/(1.f + expf(-gz));
        const float nn = tanhf(gi_lds[r][256+d] + rr*gh_lds[r][256+d]);
        updated[(row0+r)*128 + d] = (1.f - zz)*nn + zz*s_lds[r][d];
    }
}

// pred MLP layer1 + BN stats; 16 rows/block (R10)
__global__ __launch_bounds__(256) void k_pred_h(
    const float* __restrict__ updated, const float* __restrict__ w1,
    const float* __restrict__ b1, float* __restrict__ h_pred,
    double* __restrict__ stats)
{
    __shared__ float u_lds[16][128];
    const int h = threadIdx.x;
    const int row0 = blockIdx.x * 16;
    for (int f4 = h; f4 < 512; f4 += 256)
        *(float4*)&u_lds[0][f4*4] = *(const float4*)&updated[row0*128 + f4*4];
    __syncthreads();
    float acc[16];
    const float bb1 = b1[h];
#pragma unroll
    for (int r = 0; r < 16; ++r) acc[r] = bb1;
#pragma unroll 4
    for (int k = 0; k < 128; ++k) {
        const float w = w1[k*256 + h];
#pragma unroll
        for (int r = 0; r < 16; ++r) acc[r] = fmaf(u_lds[r][k], w, acc[r]);
    }
    double sum = 0.0, ssq = 0.0;
#pragma unroll
    for (int r = 0; r < 16; ++r) {
        const float v = fmaxf(acc[r], 0.f);
        h_pred[(row0+r)*256 + h] = v;
        sum += (double)v; ssq = fma((double)v, (double)v, ssq);
    }
    atomicAdd(&stats[6*256+h], sum);
    atomicAdd(&stats[7*256+h], ssq);
}

// pred BN + layer2 -> z_where_next; 32 rows/block, 128 blocks (R10).
// Block 0 also reduces KL partials.
__global__ __launch_bounds__(256) void k_pred_out(
    const float* __restrict__ h_pred, const double* __restrict__ stats,
    const float* __restrict__ g, const float* __restrict__ bbv,
    const float* __restrict__ w2, const float* __restrict__ b2,
    const float* __restrict__ klp,
    float* __restrict__ out_zw, float* __restrict__ out_kl)
{
    __shared__ float scale_lds[256], shift_lds[256];
    __shared__ float h_lds[32*256];
    __shared__ float red0[256], red1[256];
    __shared__ double kred[4];
    const int t = threadIdx.x;
    {
        const double mu  = stats[6*256+t]/4096.0;
        const double var = stats[7*256+t]/4096.0 - mu*mu;
        const float  sc  = (float)((double)g[t]/sqrt(var + 1e-5));
        scale_lds[t] = sc;
        shift_lds[t] = bbv[t] - (float)mu*sc;
    }
    const int row0 = blockIdx.x * 32;
    for (int idx = t; idx < 32*256; idx += 256)
        h_lds[idx] = h_pred[row0*256 + idx];
    __syncthreads();
    const int rl = t >> 3, q = t & 7;
    float a0 = 0.f, a1 = 0.f;
    for (int kk = 0; kk < 32; ++kk) {
        const int k = q*32 + kk;
        const float hn = fmaf(h_lds[rl*256 + k], scale_lds[k], shift_lds[k]);
        a0 = fmaf(hn, w2[k*2],   a0);
        a1 = fmaf(hn, w2[k*2+1], a1);
    }
    red0[t] = a0; red1[t] = a1;
    __syncthreads();
    if (t < 32) {
        float z0 = b2[0], z1 = b2[1];
        for (int q2 = 0; q2 < 8; ++q2) { z0 += red0[t*8+q2]; z1 += red1[t*8+q2]; }
        out_zw[(row0+t)*2]   = z0;
        out_zw[(row0+t)*2+1] = z1;
    }
    if (blockIdx.x == 0) {
        double s = 0.0;
        for (int idx = t; idx < 1024; idx += 256) s += (double)klp[idx];
        for (int off = 32; off; off >>= 1) s += __shfl_down(s, off);
        if ((t & 63) == 0) kred[t >> 6] = s;
        __syncthreads();
        if (t == 0)
            out_kl[0] = (float)((kred[0]+kred[1]+kred[2]+kred[3]) / 4096.0);
    }
}

extern "C" void kernel_launch(void* const* d_in, const int* in_sizes, int n_in,
                              void* d_out, int out_size, void* d_ws, size_t ws_size,
                              hipStream_t stream) {
    const float* states   = (const float*)d_in[0];
    const float* z_where  = (const float*)d_in[1];
    const float* actions  = (const float*)d_in[2];
    const float* gumbel   = (const float*)d_in[3];
    const float* self_w1  = (const float*)d_in[4];
    const float* self_b1  = (const float*)d_in[5];
    const float* self_g   = (const float*)d_in[6];
    const float* self_bb  = (const float*)d_in[7];
    const float* self_w2  = (const float*)d_in[8];
    const float* self_b2  = (const float*)d_in[9];
    const float* rel_w1   = (const float*)d_in[10];
    const float* rel_b1   = (const float*)d_in[11];
    const float* rel_g    = (const float*)d_in[12];
    const float* rel_bb   = (const float*)d_in[13];
    const float* rel_w2   = (const float*)d_in[14];
    const float* rel_b2   = (const float*)d_in[15];
    const float* wgt_w1   = (const float*)d_in[16];
    const float* wgt_b1   = (const float*)d_in[17];
    const float* wgt_g    = (const float*)d_in[18];
    const float* wgt_bb   = (const float*)d_in[19];
    const float* wgt_w2   = (const float*)d_in[20];
    const float* wgt_b2   = (const float*)d_in[21];
    const float* pred_w1  = (const float*)d_in[22];
    const float* pred_b1  = (const float*)d_in[23];
    const float* pred_g   = (const float*)d_in[24];
    const float* pred_bb  = (const float*)d_in[25];
    const float* pred_w2  = (const float*)d_in[26];
    const float* pred_b2  = (const float*)d_in[27];
    const float* gru_wih  = (const float*)d_in[28];
    const float* gru_whh  = (const float*)d_in[29];
    const float* gru_bih  = (const float*)d_in[30];
    const float* gru_bhh  = (const float*)d_in[31];

    char* ws = (char*)d_ws;
    float*  A_rel  = (float*) (ws + OFF_A_REL);
    float*  B_rel  = (float*) (ws + OFF_B_REL);
    float*  A_wgt  = (float*) (ws + OFF_A_WGT);
    float*  B_wgt  = (float*) (ws + OFF_B_WGT);
    float*  B_wgtT = (float*) (ws + OFF_BWT);
    float*  h_self = (float*) (ws + OFF_H_SELF);
    float*  encS   = (float*) (ws + OFF_ENC_SELF);
    float*  encR   = (float*) (ws + OFF_ENC_REL);
    float*  h_pred = (float*) (ws + OFF_H_PRED);
    float*  wihT   = (float*) (ws + OFF_WIHT);
    float*  whhT   = (float*) (ws + OFF_WHHT);
    double* stats  = (double*)(ws + OFF_STATS);
    float*  klp    = (float*) (ws + OFF_KLP);
    float*  W2p    = (float*) (ws + OFF_W2P);
    float*  c2     = (float*) (ws + OFF_C2);
    double* W2pd   = (double*)(ws + OFF_W2PD);
    double* c2w    = (double*)(ws + OFF_C2W);
    float*  sW2p   = (float*) (ws + OFF_SW2P);
    float*  sc2    = (float*) (ws + OFF_SC2);

    float* out = (float*)d_out;

    k_zero<<<8, 256, 0, stream>>>(stats);
    k_wtrans<<<384, 256, 0, stream>>>(gru_wih, gru_whh, wihT, whhT);
    k_pre<<<dim3(512, 3), 256, 0, stream>>>(states, rel_w1, rel_b1, wgt_w1, wgt_b1,
                                            z_where, actions, self_w1, self_b1,
                                            A_rel, B_rel, A_wgt, B_wgt, B_wgtT,
                                            h_self, stats);
    k_bn_stats<<<dim3(8, 64), 256, 0, stream>>>(A_rel, B_rel, A_wgt, B_wgt, stats);
    k_finalize<<<4, 256, 0, stream>>>(stats, rel_g, rel_bb, rel_w2, rel_b2,
                                      wgt_g, wgt_bb, wgt_w2, wgt_b2,
                                      self_g, self_bb, self_w2, self_b2,
                                      W2p, c2, W2pd, c2w, sW2p, sc2);
    k_main<<<1024, 256, 0, stream>>>(A_rel, B_rel, A_wgt, B_wgtT, W2pd, c2w,
                                     gumbel, W2p, c2, encR, out + OUT_WGT, klp);
    k_enc_self<<<256, 256, 0, stream>>>(h_self, sW2p, sc2, encS);
    k_gru<<<1024, 192, 0, stream>>>(encS, encR, states, wihT, whhT,
                                    gru_bih, gru_bhh, out + OUT_UPD);
    k_pred_h<<<256, 256, 0, stream>>>(out + OUT_UPD, pred_w1, pred_b1, h_pred, stats);
    k_pred_out<<<128, 256, 0, stream>>>(h_pred, stats, pred_g, pred_bb, pred_w2, pred_b2,
                                        klp, out + OUT_ZWN, out + OUT_KL);
}

// Round 13
// 195.267 us; speedup vs baseline: 1.2639x; 1.2639x over previous
//
#include <hip/hip_runtime.h>
#include <math.h>

#define BATCH 64
#define NOBJ  64
#define DDIM  128
#define HDIM  256
#define ROWS  (BATCH*NOBJ)    // 4096
#define PAIRS (ROWS*NOBJ)     // 262144

// ---- workspace layout (bytes) ----
#define OFF_A_REL    (0ull)
#define OFF_B_REL    (4ull<<20)
#define OFF_A_WGT    (8ull<<20)      // f32
#define OFF_B_WGT    (12ull<<20)     // f32 (row-major, for bn_stats)
#define OFF_BWT      (16ull<<20)     // f32 transposed [b][k][j] (for k_main)
#define OFF_H_SELF   (20ull<<20)
#define OFF_ENC_SELF (24ull<<20)
#define OFF_ENC_REL  (26ull<<20)
#define OFF_H_PRED   (28ull<<20)
#define OFF_STATS    (32ull<<20)     // 8 x 256 doubles
#define OFF_KLP      (OFF_STATS + 16384)   // 1024 f32 partials
#define OFF_W2P      (OFF_STATS + 65536)   // rel folded w2: 256x128 f32
#define OFF_C2       (OFF_W2P + 128*1024)  // 128 f32
#define OFF_W2PD     (OFF_C2 + 512)        // wgt folded w2: 512 f64
#define OFF_C2W      (OFF_W2PD + 4096)     // 2 f64
#define OFF_SW2P     (OFF_C2W + 256)       // self folded w2
#define OFF_SC2      (OFF_SW2P + 128*1024)

// ---- output layout (floats) ----
#define OUT_UPD 0
#define OUT_ZWN (ROWS*DDIM)          // 524288
#define OUT_WGT (OUT_ZWN + ROWS*2)   // 532480
#define OUT_KL  (OUT_WGT + PAIRS)    // 794624

// zero the stats accumulators
__global__ __launch_bounds__(256) void k_zero(double* __restrict__ p)
{
    p[blockIdx.x*256 + threadIdx.x] = 0.0;
}

// GEMM-tiled pre-activations, pair-merged, 8 rows/block (R10 version).
__global__ __launch_bounds__(256) void k_pre(
    const float* __restrict__ states,
    const float* __restrict__ rel_w1, const float* __restrict__ rel_b1,
    const float* __restrict__ wgt_w1, const float* __restrict__ wgt_b1,
    const float* __restrict__ z_where, const float* __restrict__ actions,
    const float* __restrict__ self_w1, const float* __restrict__ self_b1,
    float* __restrict__ A_rel, float* __restrict__ B_rel,
    float* __restrict__ A_wgt, float* __restrict__ B_wgt,
    float* __restrict__ B_wgtT, float* __restrict__ h_self,
    double* __restrict__ stats)
{
    const int t = threadIdx.x;
    const int view = blockIdx.y;

    if (view == 2) {
        if (blockIdx.x >= 256) return;
        const int row0 = blockIdx.x * 16;
        const float w_zw0 = self_w1[0*256+t], w_zw1 = self_w1[1*256+t];
        const float w_a0  = self_w1[66*256+t], w_a1 = self_w1[67*256+t];
        const float bb1 = self_b1[t];
        double sum = 0.0, ssq = 0.0;
        for (int r = 0; r < 16; ++r) {
            const int row = row0 + r;
            const int b = row >> 6, i = row & 63;
            const float zw0 = z_where[row*2], zw1 = z_where[row*2+1];
            const float a0 = actions[b*2], a1 = actions[b*2+1];
            float v = self_w1[(2+i)*256+t] + bb1;
            v = fmaf(zw0, w_zw0, v); v = fmaf(zw1, w_zw1, v);
            v = fmaf(a0, w_a0, v);   v = fmaf(a1, w_a1, v);
            v = fmaxf(v, 0.f);
            h_self[row*256+t] = v;
            sum += (double)v; ssq = fma((double)v, (double)v, ssq);
        }
        atomicAdd(&stats[4*256+t], sum);
        atomicAdd(&stats[5*256+t], ssq);
        return;
    }

    const int row0 = blockIdx.x * 8;
    __shared__ float s_tile[8][128];
    for (int f4 = t; f4 < 256; f4 += 256)
        *(float4*)&s_tile[0][f4*4] = *(const float4*)&states[row0*128 + f4*4];
    __syncthreads();

    const float* wbase = (view == 0) ? rel_w1 : wgt_w1;
    const float* wpA = wbase + t;
    const float* wpB = wbase + 128*256 + t;
    float accA[8], accB[8];
#pragma unroll
    for (int r = 0; r < 8; ++r) { accA[r] = 0.f; accB[r] = 0.f; }
#pragma unroll 4
    for (int k = 0; k < 128; ++k) {
        const float wvA = wpA[k*256];
        const float wvB = wpB[k*256];
#pragma unroll
        for (int r = 0; r < 8; ++r) {
            const float s = s_tile[r][k];
            accA[r] = fmaf(s, wvA, accA[r]);
            accB[r] = fmaf(s, wvB, accB[r]);
        }
    }

    if (view == 0) {
        const float bias = rel_b1[t];
#pragma unroll
        for (int r = 0; r < 8; ++r) {
            A_rel[(row0+r)*256 + t] = accA[r] + bias;
            B_rel[(row0+r)*256 + t] = accB[r];
        }
    } else {
        const float bias = wgt_b1[t];
#pragma unroll
        for (int r = 0; r < 8; ++r) {
            A_wgt[(row0+r)*256 + t] = accA[r] + bias;
            B_wgt[(row0+r)*256 + t] = accB[r];
        }
        const int b = row0 >> 6, j0 = row0 & 63;
        float* bt = &B_wgtT[((size_t)b*256 + t)*64 + j0];
        *(float4*)(bt+0) = make_float4(accB[0], accB[1], accB[2], accB[3]);
        *(float4*)(bt+4) = make_float4(accB[4], accB[5], accB[6], accB[7]);
    }
}

// BN stats over all 262144 pairs. rel: f32; wgt: f64 (argmax-critical). R4 config.
__global__ __launch_bounds__(256) void k_bn_stats(
    const float* __restrict__ A_rel, const float* __restrict__ B_rel,
    const float* __restrict__ A_wgt, const float* __restrict__ B_wgt,
    double* __restrict__ stats)
{
    const int h = threadIdx.x;
    const int b = blockIdx.y, i0 = blockIdx.x * 8;
    float ar[8], aw[8];
#pragma unroll
    for (int r = 0; r < 8; ++r) {
        ar[r] = A_rel[(b*64 + i0 + r)*256 + h];
        aw[r] = A_wgt[(b*64 + i0 + r)*256 + h];
    }
    float  srel0 = 0.f, ssrel0 = 0.f, srel1 = 0.f, ssrel1 = 0.f;
    double swgt = 0.0, sswgt = 0.0;
    for (int j = 0; j < 64; j += 2) {
        const float br0 = B_rel[(b*64+j)*256 + h];
        const float bw0 = B_wgt[(b*64+j)*256 + h];
        const float br1 = B_rel[(b*64+j+1)*256 + h];
        const float bw1 = B_wgt[(b*64+j+1)*256 + h];
#pragma unroll
        for (int r = 0; r < 8; ++r) {
            const float v0 = fmaxf(ar[r] + br0, 0.f);
            srel0 += v0; ssrel0 = fmaf(v0, v0, ssrel0);
            const float vw0 = fmaxf(aw[r] + bw0, 0.f);
            swgt += (double)vw0; sswgt = fma((double)vw0, (double)vw0, sswgt);
        }
#pragma unroll
        for (int r = 0; r < 8; ++r) {
            const float v1 = fmaxf(ar[r] + br1, 0.f);
            srel1 += v1; ssrel1 = fmaf(v1, v1, ssrel1);
            const float vw1 = fmaxf(aw[r] + bw1, 0.f);
            swgt += (double)vw1; sswgt = fma((double)vw1, (double)vw1, sswgt);
        }
    }
    atomicAdd(&stats[0*256+h], (double)(srel0 + srel1));
    atomicAdd(&stats[1*256+h], (double)(ssrel0 + ssrel1));
    atomicAdd(&stats[2*256+h], swgt);
    atomicAdd(&stats[3*256+h], sswgt);
}

// fold BN scale/shift into layer-2 weights; grid = 4 blocks
__global__ __launch_bounds__(256) void k_finalize(
    const double* __restrict__ stats,
    const float* __restrict__ rel_g, const float* __restrict__ rel_bb,
    const float* __restrict__ rel_w2, const float* __restrict__ rel_b2,
    const float* __restrict__ wgt_g, const float* __restrict__ wgt_bb,
    const float* __restrict__ wgt_w2, const float* __restrict__ wgt_b2,
    const float* __restrict__ self_g, const float* __restrict__ self_bb,
    const float* __restrict__ self_w2, const float* __restrict__ self_b2,
    float* __restrict__ W2p, float* __restrict__ c2,
    double* __restrict__ W2pd, double* __restrict__ c2w,
    float* __restrict__ sW2p, float* __restrict__ sc2)
{
    __shared__ float  rscale[256], rshift[256], sscale[256], sshift[256];
    __shared__ double wshift[256];
    const int k = threadIdx.x;
    {
        const double cnt = 262144.0;
        double mu  = stats[0*256+k]/cnt;
        double var = stats[1*256+k]/cnt - mu*mu;
        float  sc  = (float)((double)rel_g[k] / sqrt(var + 1e-5));
        rscale[k] = sc;
        rshift[k] = rel_bb[k] - (float)mu * sc;
        double muw  = stats[2*256+k]/cnt;
        double varw = stats[3*256+k]/cnt - muw*muw;
        double scw  = (double)wgt_g[k] / sqrt(varw + 1e-5);
        wshift[k]   = (double)wgt_bb[k] - muw*scw;
        if (blockIdx.x == 0) {
            W2pd[2*k]   = scw * (double)wgt_w2[2*k];
            W2pd[2*k+1] = scw * (double)wgt_w2[2*k+1];
        }
        const double cnts = 4096.0;
        double mus  = stats[4*256+k]/cnts;
        double vars = stats[5*256+k]/cnts - mus*mus;
        float  scs  = (float)((double)self_g[k] / sqrt(vars + 1e-5));
        sscale[k] = scs;
        sshift[k] = self_bb[k] - (float)mus*scs;
    }
    __syncthreads();
    const int base = blockIdx.x * 8192;
    for (int idx = base + k; idx < base + 8192; idx += 256) {
        const int kk = idx >> 7;
        W2p[idx]  = rscale[kk]*rel_w2[idx];
        sW2p[idx] = sscale[kk]*self_w2[idx];
    }
    if (blockIdx.x == 0) {
        if (k < 128) {
            float acc = rel_b2[k], accs = self_b2[k];
            for (int kk = 0; kk < 256; ++kk) {
                acc  = fmaf(rshift[kk], rel_w2[kk*128+k], acc);
                accs = fmaf(sshift[kk], self_w2[kk*128+k], accs);
            }
            c2[k] = acc; sc2[k] = accs;
        }
        if (k < 2) {
            double acc = (double)wgt_b2[k];
            for (int kk = 0; kk < 256; ++kk) acc += wshift[kk]*(double)wgt_w2[kk*2+k];
            c2w[k] = acc;
        }
    }
}

// 4 rows per block; 1024 blocks, 256 threads.
__global__ __launch_bounds__(256) void k_main(
    const float* __restrict__ A_rel, const float* __restrict__ B_rel,
    const float* __restrict__ A_wgt, const float* __restrict__ B_wgtT,
    const double* __restrict__ W2pd, const double* __restrict__ c2w,
    const float* __restrict__ gumbel,
    const float* __restrict__ W2p, const float* __restrict__ c2,
    float* __restrict__ enc_rel, float* __restrict__ weight_out,
    float* __restrict__ klp)
{
    __shared__ float  a_lds[4][256];
    __shared__ double w2_lds[512];
    __shared__ double red0[4][4][64], red1[4][4][64];
    __shared__ float  w_lds[4][64];
    __shared__ float  klred[256];
    __shared__ float  h_lds[4][256];
    __shared__ float  redf[4][256];
    const int t = threadIdx.x;
    const int blk = blockIdx.x;          // 0..1023
    const int row0 = blk * 4;
    const int b = row0 >> 6;

    w2_lds[t]     = W2pd[t];
    w2_lds[256+t] = W2pd[256+t];
    float a_rel[4];
#pragma unroll
    for (int r = 0; r < 4; ++r) {
        a_lds[r][t] = A_wgt[(row0+r)*256 + t];
        a_rel[r]    = A_rel[(row0+r)*256 + t];
    }
    __syncthreads();

    // ---- phase A: logits, k wave-uniform (f64 accumulation) ----
    {
        const int j = t & 63, q = t >> 6;
        double acc0[4] = {0,0,0,0}, acc1[4] = {0,0,0,0};
        const float* btp = &B_wgtT[((size_t)b*256 + q*64)*64 + j];
#pragma unroll 4
        for (int kk = 0; kk < 64; ++kk) {
            const int k = q*64 + kk;
            const float  bw = btp[kk*64];
            const double w0 = w2_lds[2*k], w1 = w2_lds[2*k+1];
#pragma unroll
            for (int r = 0; r < 4; ++r) {
                const double hw = (double)fmaxf(a_lds[r][k] + bw, 0.f);
                acc0[r] = fma(hw, w0, acc0[r]);
                acc1[r] = fma(hw, w1, acc1[r]);
            }
        }
#pragma unroll
        for (int r = 0; r < 4; ++r) { red0[r][q][j] = acc0[r]; red1[r][q][j] = acc1[r]; }
    }
    __syncthreads();

    // ---- finalize logits: t -> (r, j); weight + KL ----
    {
        const int r = t >> 6, j = t & 63;
        const double l0 = red0[r][0][j]+red0[r][1][j]+red0[r][2][j]+red0[r][3][j] + c2w[0];
        const double l1 = red1[r][0][j]+red1[r][1][j]+red1[r][2][j]+red1[r][3][j] + c2w[1];
        const int row = row0 + r;
        const float g0 = gumbel[(row*64+j)*2], g1 = gumbel[(row*64+j)*2+1];
        float w = (l0 + (double)g0 >= l1 + (double)g1) ? 1.f : 0.f;
        if (j == (row & 63)) w = 0.f;      // (1-eye) mask
        w_lds[r][j] = w;
        weight_out[row*64 + j] = w;
        const float lf0 = (float)l0, lf1 = (float)l1;
        const float m = fmaxf(lf0, lf1);
        const float e0 = expf(lf0 - m), e1 = expf(lf1 - m);
        const float s = e0 + e1;
        const float p0 = e0/s, p1 = e1/s;
        const float lp0 = -2.9957323f;   // log(0.05)
        const float lp1 = -0.05129329f;  // log(0.95)
        klred[t] = p0*(logf(p0+1e-16f) - lp0) + p1*(logf(p1+1e-16f) - lp1);
    }
    __syncthreads();
    if (t < 64) {
        float s = klred[t] + klred[t+64] + klred[t+128] + klred[t+192];
        for (int off = 32; off; off >>= 1) s += __shfl_down(s, off);
        if (t == 0) klp[blk] = s;
    }

    // ---- phase B: weighted relu accumulation (t = k), branch-free ----
    float sumw[4] = {0,0,0,0};
    {
        float g[4] = {0,0,0,0};
#pragma unroll 4
        for (int j = 0; j < 64; ++j) {
            const float br = B_rel[(b*64+j)*256 + t];
#pragma unroll
            for (int r = 0; r < 4; ++r) {
                const float w = w_lds[r][j];
                sumw[r] += w;
                g[r] = fmaf(w, fmaxf(a_rel[r] + br, 0.f), g[r]);
            }
        }
#pragma unroll
        for (int r = 0; r < 4; ++r) h_lds[r][t] = g[r];
    }
    __syncthreads();
    // ---- folded matvec 256->128, amortized over 4 rows ----
    {
        const int d = t & 127, half = t >> 7;
        float acc[4] = {0,0,0,0};
        const float* wp = &W2p[half*128*128 + d];
#pragma unroll 2
        for (int kk = 0; kk < 128; ++kk) {
            const float wv = wp[kk*128];
#pragma unroll
            for (int r = 0; r < 4; ++r)
                acc[r] = fmaf(h_lds[r][half*128 + kk], wv, acc[r]);
        }
#pragma unroll
        for (int r = 0; r < 4; ++r) redf[r][t] = acc[r];
    }
    __syncthreads();
    if (t < 128) {
#pragma unroll
        for (int r = 0; r < 4; ++r)
            enc_rel[(row0+r)*128 + t] = redf[r][t] + redf[r][t+128] + sumw[r]*c2[t];
    }
}

// enc_self = BN(h_self) @ self_w2 + b2 via folded weights; 16 rows/block (R10)
__global__ __launch_bounds__(256) void k_enc_self(
    const float* __restrict__ h_self, const float* __restrict__ sW2p,
    const float* __restrict__ sc2, float* __restrict__ enc_self)
{
    __shared__ float h_lds[16*256];
    const int t = threadIdx.x;
    const int row0 = blockIdx.x * 16;
    for (int f4 = t; f4 < 1024; f4 += 256)
        *(float4*)&h_lds[f4*4] = *(const float4*)&h_self[row0*256 + f4*4];
    __syncthreads();
    const int d = t & 127, half = t >> 7;
    float acc[16];
#pragma unroll
    for (int r = 0; r < 16; ++r) acc[r] = 0.f;
    for (int kk = 0; kk < 128; ++kk) {
        const int k = half*128 + kk;
        const float wv = sW2p[k*128 + d];
#pragma unroll
        for (int r = 0; r < 16; ++r) acc[r] = fmaf(h_lds[r*256 + k], wv, acc[r]);
    }
    __syncthreads();
#pragma unroll
    for (int r = 0; r < 16; ++r) h_lds[r*256 + t] = acc[r];
    __syncthreads();
    for (int idx = t; idx < 16*128; idx += 256) {
        const int r = idx >> 7, dd = idx & 127;
        enc_self[(row0+r)*128 + dd] = h_lds[r*256 + dd] + h_lds[r*256 + 128 + dd] + sc2[dd];
    }
}

// GRU cell v6 (R10 version): 192 threads, 2 cols/thread, 4 rows, 1024 blocks.
// Coalesced scalar weight loads (lane-contiguous wih[k*384+c]); explicit
// float4 LDS reads keep ds_read_b128.
__global__ __launch_bounds__(192) void k_gru(
    const float* __restrict__ enc_self, const float* __restrict__ enc_rel,
    const float* __restrict__ states,
    const float* __restrict__ wih, const float* __restrict__ whh,
    const float* __restrict__ bih, const float* __restrict__ bhh,
    float* __restrict__ updated)
{
    __shared__ float x_lds[4][256];
    __shared__ float s_lds[4][128];
    __shared__ float gi_lds[4][384];
    __shared__ float gh_lds[4][384];
    const int t = threadIdx.x;
    const int row0 = blockIdx.x * 4;
    for (int idx = t; idx < 4*256; idx += 192) {
        const int r = idx >> 8, k = idx & 255;
        x_lds[r][k] = (k < 128) ? enc_self[(row0+r)*128 + k]
                                : enc_rel[(row0+r)*128 + (k-128)];
    }
    for (int idx = t; idx < 4*128; idx += 192) {
        const int r = idx >> 7, k = idx & 127;
        s_lds[r][k] = states[(row0+r)*128 + k];
    }
    __syncthreads();
    const int c0 = t, c1 = t + 192;
    float gi0[4], gh0[4], gi1[4], gh1[4];
    const float bi0 = bih[c0], bh0 = bhh[c0];
    const float bi1 = bih[c1], bh1 = bhh[c1];
#pragma unroll
    for (int r = 0; r < 4; ++r) { gi0[r] = bi0; gh0[r] = bh0; gi1[r] = bi1; gh1[r] = bh1; }

    // ---- phase 1: k = 0..127, both streams ----
    for (int k0 = 0; k0 < 128; k0 += 4) {
        float4 xv[4], sv[4];
#pragma unroll
        for (int r = 0; r < 4; ++r) {
            xv[r] = *(const float4*)&x_lds[r][k0];
            sv[r] = *(const float4*)&s_lds[r][k0];
        }
        float wi0[4], wi1[4], wh0[4], wh1[4];
#pragma unroll
        for (int kk = 0; kk < 4; ++kk) {
            wi0[kk] = wih[(k0+kk)*384 + c0];
            wi1[kk] = wih[(k0+kk)*384 + c1];
            wh0[kk] = whh[(k0+kk)*384 + c0];
            wh1[kk] = whh[(k0+kk)*384 + c1];
        }
#pragma unroll
        for (int kk = 0; kk < 4; ++kk) {
#pragma unroll
            for (int r = 0; r < 4; ++r) {
                const float x = ((const float*)&xv[r])[kk];
                const float s = ((const float*)&sv[r])[kk];
                gi0[r] = fmaf(x, wi0[kk], gi0[r]);
                gi1[r] = fmaf(x, wi1[kk], gi1[r]);
                gh0[r] = fmaf(s, wh0[kk], gh0[r]);
                gh1[r] = fmaf(s, wh1[kk], gh1[r]);
            }
        }
    }
    // ---- phase 2: k = 128..255, gi only ----
    for (int k0 = 128; k0 < 256; k0 += 4) {
        float4 xv[4];
#pragma unroll
        for (int r = 0; r < 4; ++r)
            xv[r] = *(const float4*)&x_lds[r][k0];
        float wi0[4], wi1[4];
#pragma unroll
        for (int kk = 0; kk < 4; ++kk) {
            wi0[kk] = wih[(k0+kk)*384 + c0];
            wi1[kk] = wih[(k0+kk)*384 + c1];
        }
#pragma unroll
        for (int kk = 0; kk < 4; ++kk) {
#pragma unroll
            for (int r = 0; r < 4; ++r) {
                const float x = ((const float*)&xv[r])[kk];
                gi0[r] = fmaf(x, wi0[kk], gi0[r]);
                gi1[r] = fmaf(x, wi1[kk], gi1[r]);
            }
        }
    }
#pragma unroll
    for (int r = 0; r < 4; ++r) {
        gi_lds[r][c0] = gi0[r]; gi_lds[r][c1] = gi1[r];
        gh_lds[r][c0] = gh0[r]; gh_lds[r][c1] = gh1[r];
    }
    __syncthreads();
    for (int idx = t; idx < 4*128; idx += 192) {
        const int r = idx >> 7, d = idx & 127;
        const float gr = gi_lds[r][d]       + gh_lds[r][d];
        const float gz = gi_lds[r][128+d]   + gh_lds[r][128+d];
        const float rr = 1.f/(1.f + expf(-gr));
        const float zz = 1.f/(1.f + expf(-gz));
        const float nn = tanhf(gi_lds[r][256+d] + rr*gh_lds[r][256+d]);
        updated[(row0+r)*128 + d] = (1.f - zz)*nn + zz*s_lds[r][d];
    }
}

// pred MLP layer1 + BN stats; 16 rows/block (R10)
__global__ __launch_bounds__(256) void k_pred_h(
    const float* __restrict__ updated, const float* __restrict__ w1,
    const float* __restrict__ b1, float* __restrict__ h_pred,
    double* __restrict__ stats)
{
    __shared__ float u_lds[16][128];
    const int h = threadIdx.x;
    const int row0 = blockIdx.x * 16;
    for (int f4 = h; f4 < 512; f4 += 256)
        *(float4*)&u_lds[0][f4*4] = *(const float4*)&updated[row0*128 + f4*4];
    __syncthreads();
    float acc[16];
    const float bb1 = b1[h];
#pragma unroll
    for (int r = 0; r < 16; ++r) acc[r] = bb1;
#pragma unroll 4
    for (int k = 0; k < 128; ++k) {
        const float w = w1[k*256 + h];
#pragma unroll
        for (int r = 0; r < 16; ++r) acc[r] = fmaf(u_lds[r][k], w, acc[r]);
    }
    double sum = 0.0, ssq = 0.0;
#pragma unroll
    for (int r = 0; r < 16; ++r) {
        const float v = fmaxf(acc[r], 0.f);
        h_pred[(row0+r)*256 + h] = v;
        sum += (double)v; ssq = fma((double)v, (double)v, ssq);
    }
    atomicAdd(&stats[6*256+h], sum);
    atomicAdd(&stats[7*256+h], ssq);
}

// pred BN + layer2 -> z_where_next; 32 rows/block, 128 blocks (R10).
// Block 0 also reduces KL partials.
__global__ __launch_bounds__(256) void k_pred_out(
    const float* __restrict__ h_pred, const double* __restrict__ stats,
    const float* __restrict__ g, const float* __restrict__ bbv,
    const float* __restrict__ w2, const float* __restrict__ b2,
    const float* __restrict__ klp,
    float* __restrict__ out_zw, float* __restrict__ out_kl)
{
    __shared__ float scale_lds[256], shift_lds[256];
    __shared__ float h_lds[32*256];
    __shared__ float red0[256], red1[256];
    __shared__ double kred[4];
    const int t = threadIdx.x;
    {
        const double mu  = stats[6*256+t]/4096.0;
        const double var = stats[7*256+t]/4096.0 - mu*mu;
        const float  sc  = (float)((double)g[t]/sqrt(var + 1e-5));
        scale_lds[t] = sc;
        shift_lds[t] = bbv[t] - (float)mu*sc;
    }
    const int row0 = blockIdx.x * 32;
    for (int idx = t; idx < 32*256; idx += 256)
        h_lds[idx] = h_pred[row0*256 + idx];
    __syncthreads();
    const int rl = t >> 3, q = t & 7;
    float a0 = 0.f, a1 = 0.f;
    for (int kk = 0; kk < 32; ++kk) {
        const int k = q*32 + kk;
        const float hn = fmaf(h_lds[rl*256 + k], scale_lds[k], shift_lds[k]);
        a0 = fmaf(hn, w2[k*2],   a0);
        a1 = fmaf(hn, w2[k*2+1], a1);
    }
    red0[t] = a0; red1[t] = a1;
    __syncthreads();
    if (t < 32) {
        float z0 = b2[0], z1 = b2[1];
        for (int q2 = 0; q2 < 8; ++q2) { z0 += red0[t*8+q2]; z1 += red1[t*8+q2]; }
        out_zw[(row0+t)*2]   = z0;
        out_zw[(row0+t)*2+1] = z1;
    }
    if (blockIdx.x == 0) {
        double s = 0.0;
        for (int idx = t; idx < 1024; idx += 256) s += (double)klp[idx];
        for (int off = 32; off; off >>= 1) s += __shfl_down(s, off);
        if ((t & 63) == 0) kred[t >> 6] = s;
        __syncthreads();
        if (t == 0)
            out_kl[0] = (float)((kred[0]+kred[1]+kred[2]+kred[3]) / 4096.0);
    }
}

extern "C" void kernel_launch(void* const* d_in, const int* in_sizes, int n_in,
                              void* d_out, int out_size, void* d_ws, size_t ws_size,
                              hipStream_t stream) {
    const float* states   = (const float*)d_in[0];
    const float* z_where  = (const float*)d_in[1];
    const float* actions  = (const float*)d_in[2];
    const float* gumbel   = (const float*)d_in[3];
    const float* self_w1  = (const float*)d_in[4];
    const float* self_b1  = (const float*)d_in[5];
    const float* self_g   = (const float*)d_in[6];
    const float* self_bb  = (const float*)d_in[7];
    const float* self_w2  = (const float*)d_in[8];
    const float* self_b2  = (const float*)d_in[9];
    const float* rel_w1   = (const float*)d_in[10];
    const float* rel_b1   = (const float*)d_in[11];
    const float* rel_g    = (const float*)d_in[12];
    const float* rel_bb   = (const float*)d_in[13];
    const float* rel_w2   = (const float*)d_in[14];
    const float* rel_b2   = (const float*)d_in[15];
    const float* wgt_w1   = (const float*)d_in[16];
    const float* wgt_b1   = (const float*)d_in[17];
    const float* wgt_g    = (const float*)d_in[18];
    const float* wgt_bb   = (const float*)d_in[19];
    const float* wgt_w2   = (const float*)d_in[20];
    const float* wgt_b2   = (const float*)d_in[21];
    const float* pred_w1  = (const float*)d_in[22];
    const float* pred_b1  = (const float*)d_in[23];
    const float* pred_g   = (const float*)d_in[24];
    const float* pred_bb  = (const float*)d_in[25];
    const float* pred_w2  = (const float*)d_in[26];
    const float* pred_b2  = (const float*)d_in[27];
    const float* gru_wih  = (const float*)d_in[28];
    const float* gru_whh  = (const float*)d_in[29];
    const float* gru_bih  = (const float*)d_in[30];
    const float* gru_bhh  = (const float*)d_in[31];

    char* ws = (char*)d_ws;
    float*  A_rel  = (float*) (ws + OFF_A_REL);
    float*  B_rel  = (float*) (ws + OFF_B_REL);
    float*  A_wgt  = (float*) (ws + OFF_A_WGT);
    float*  B_wgt  = (float*) (ws + OFF_B_WGT);
    float*  B_wgtT = (float*) (ws + OFF_BWT);
    float*  h_self = (float*) (ws + OFF_H_SELF);
    float*  encS   = (float*) (ws + OFF_ENC_SELF);
    float*  encR   = (float*) (ws + OFF_ENC_REL);
    float*  h_pred = (float*) (ws + OFF_H_PRED);
    double* stats  = (double*)(ws + OFF_STATS);
    float*  klp    = (float*) (ws + OFF_KLP);
    float*  W2p    = (float*) (ws + OFF_W2P);
    float*  c2     = (float*) (ws + OFF_C2);
    double* W2pd   = (double*)(ws + OFF_W2PD);
    double* c2w    = (double*)(ws + OFF_C2W);
    float*  sW2p   = (float*) (ws + OFF_SW2P);
    float*  sc2    = (float*) (ws + OFF_SC2);

    float* out = (float*)d_out;

    k_zero<<<8, 256, 0, stream>>>(stats);
    k_pre<<<dim3(512, 3), 256, 0, stream>>>(states, rel_w1, rel_b1, wgt_w1, wgt_b1,
                                            z_where, actions, self_w1, self_b1,
                                            A_rel, B_rel, A_wgt, B_wgt, B_wgtT,
                                            h_self, stats);
    k_bn_stats<<<dim3(8, 64), 256, 0, stream>>>(A_rel, B_rel, A_wgt, B_wgt, stats);
    k_finalize<<<4, 256, 0, stream>>>(stats, rel_g, rel_bb, rel_w2, rel_b2,
                                      wgt_g, wgt_bb, wgt_w2, wgt_b2,
                                      self_g, self_bb, self_w2, self_b2,
                                      W2p, c2, W2pd, c2w, sW2p, sc2);
    k_main<<<1024, 256, 0, stream>>>(A_rel, B_rel, A_wgt, B_wgtT, W2pd, c2w,
                                     gumbel, W2p, c2, encR, out + OUT_WGT, klp);
    k_enc_self<<<256, 256, 0, stream>>>(h_self, sW2p, sc2, encS);
    k_gru<<<1024, 192, 0, stream>>>(encS, encR, states, gru_wih, gru_whh,
                                    gru_bih, gru_bhh, out + OUT_UPD);
    k_pred_h<<<256, 256, 0, stream>>>(out + OUT_UPD, pred_w1, pred_b1, h_pred, stats);
    k_pred_out<<<128, 256, 0, stream>>>(h_pred, stats, pred_g, pred_bb, pred_w2, pred_b2,
                                        klp, out + OUT_ZWN, out + OUT_KL);
}